// Round 2
// baseline (10359.856 us; speedup 1.0000x reference)
//
#include <hip/hip_runtime.h>
#include <cstddef>

#define N_NODES 20000
#define N_EDGES 320000
#define IN_CH   64
#define HID     512
#define G4      2048
#define CH      5000          // LSTM row-chunk (4 chunks); CH*G4 == N_NODES*HID exactly
#define BN_EPS  1e-5f

__device__ __forceinline__ float sigmoidf_(float x) {
  return 1.0f / (1.0f + expf(-x));
}

// ---------------- zero fill (graph-capture-safe replacement for hipMemsetAsync) ----
__global__ __launch_bounds__(256) void zero_k(float* __restrict__ p, size_t n) {
  size_t i = ((size_t)blockIdx.x * 256 + threadIdx.x) * 4;
  if (i + 3 < n) {
    *(float4*)&p[i] = make_float4(0.f, 0.f, 0.f, 0.f);
  } else {
    for (; i < n; i++) p[i] = 0.f;
  }
}

// ---------------- GEMM: C[M,NC] (+)= A[M,K] @ B[K,NC] (+ bias) ----------------
// BM=BN=64, BK=16, 256 threads, 4x4 microtile per thread.
// Requires NC % 64 == 0, K % 16 == 0. M-edge guarded.
__global__ __launch_bounds__(256) void gemm_k(
    const float* __restrict__ A, const float* __restrict__ B,
    float* __restrict__ C, const float* __restrict__ bias,
    int M, int K, int NC, int lda, int ldb, int ldc, int acc)
{
  __shared__ float As[16][68];   // A^T tile; row stride 68 floats = 272 B (16B-aligned)
  __shared__ float Bs[16][64];
  const int row0 = blockIdx.x * 64;
  const int col0 = blockIdx.y * 64;
  const int t  = threadIdx.x;
  const int tx = t & 15, ty = t >> 4;
  float accr[4][4] = {};
  for (int k0 = 0; k0 < K; k0 += 16) {
    #pragma unroll
    for (int i = 0; i < 4; i++) {
      int idx = t + i * 256;
      int r = idx >> 4, c = idx & 15;
      int gr = row0 + r;
      As[c][r] = (gr < M) ? A[(size_t)gr * lda + (k0 + c)] : 0.0f;
    }
    #pragma unroll
    for (int i = 0; i < 4; i++) {
      int idx = t + i * 256;
      int r = idx >> 6, c = idx & 63;
      Bs[r][c] = B[(size_t)(k0 + r) * ldb + (col0 + c)];
    }
    __syncthreads();
    #pragma unroll
    for (int kk = 0; kk < 16; kk++) {
      const float4 a4 = *(const float4*)&As[kk][ty * 4];
      const float4 b4 = *(const float4*)&Bs[kk][tx * 4];
      const float a[4] = {a4.x, a4.y, a4.z, a4.w};
      const float b[4] = {b4.x, b4.y, b4.z, b4.w};
      #pragma unroll
      for (int m = 0; m < 4; m++)
        #pragma unroll
        for (int n = 0; n < 4; n++)
          accr[m][n] = fmaf(a[m], b[n], accr[m][n]);
    }
    __syncthreads();
  }
  #pragma unroll
  for (int m = 0; m < 4; m++) {
    int gr = row0 + ty * 4 + m;
    if (gr >= M) continue;
    float* cp = &C[(size_t)gr * ldc + col0 + tx * 4];
    float4 o;
    if (acc)       o = *(const float4*)cp;
    else if (bias) o = *(const float4*)&bias[col0 + tx * 4];
    else           o = make_float4(0.f, 0.f, 0.f, 0.f);
    o.x += accr[m][0]; o.y += accr[m][1]; o.z += accr[m][2]; o.w += accr[m][3];
    *(float4*)cp = o;
  }
}

// ---------------- edge scatter: H[dst,:] += ew * XW[src,:] ----------------
// 128 threads per edge, 4 cols per thread
__global__ __launch_bounds__(256) void scatter_k(
    const float* __restrict__ XW, const int* __restrict__ src,
    const int* __restrict__ dst, const float* __restrict__ ew,
    float* __restrict__ H)
{
  size_t gid = (size_t)blockIdx.x * 256 + threadIdx.x;
  int e  = (int)(gid >> 7);
  int c4 = (int)(gid & 127) << 2;
  if (e >= N_EDGES) return;
  int s = src[e], d = dst[e];
  float w = ew[e];
  const float4 v = *(const float4*)&XW[(size_t)s * HID + c4];
  float* hp = &H[(size_t)d * HID + c4];
  atomicAdd(hp + 0, w * v.x);
  atomicAdd(hp + 1, w * v.y);
  atomicAdd(hp + 2, w * v.z);
  atomicAdd(hp + 3, w * v.w);
}

// ---------------- BN stats: per-column sum and sumsq over rows ----------------
// block = 256 (64 cols x 4 row-lanes); grid = (8 col groups, 64 row groups)
__global__ __launch_bounds__(256) void bn_stats_k(
    const float* __restrict__ H, float* __restrict__ stats, int N)
{
  const int tx = threadIdx.x & 63;
  const int ty = threadIdx.x >> 6;
  const int col = blockIdx.x * 64 + tx;
  float s1 = 0.f, s2 = 0.f;
  for (int r = blockIdx.y * 4 + ty; r < N; r += gridDim.y * 4) {
    float v = H[(size_t)r * HID + col];
    s1 += v; s2 += v * v;
  }
  __shared__ float red[2][4][64];
  red[0][ty][tx] = s1;
  red[1][ty][tx] = s2;
  __syncthreads();
  if (ty == 0) {
    s1 = red[0][0][tx] + red[0][1][tx] + red[0][2][tx] + red[0][3][tx];
    s2 = red[1][0][tx] + red[1][1][tx] + red[1][2][tx] + red[1][3][tx];
    atomicAdd(&stats[col], s1);
    atomicAdd(&stats[HID + col], s2);
  }
}

// ---------------- BN apply + ReLU (in-place safe) ----------------
__global__ __launch_bounds__(256) void bn_apply_k(
    const float* __restrict__ H, const float* __restrict__ stats,
    const float* __restrict__ gamma, const float* __restrict__ beta,
    float* __restrict__ out, int N)
{
  size_t gid = (size_t)blockIdx.x * 256 + threadIdx.x;
  size_t idx = gid * 4;
  if (idx >= (size_t)N * HID) return;
  int col = (int)(idx & (HID - 1));
  const float4 v = *(const float4*)&H[idx];
  float r[4] = {v.x, v.y, v.z, v.w};
  float4 o;
  float* op = &o.x;
  #pragma unroll
  for (int i = 0; i < 4; i++) {
    int c = col + i;
    float mean = stats[c] * (1.0f / N);
    float var  = stats[HID + c] * (1.0f / N) - mean * mean;
    float scale = gamma[c] / sqrtf(var + BN_EPS);
    float shift = beta[c] - mean * scale;
    op[i] = fmaxf(fmaf(r[i], scale, shift), 0.0f);
  }
  *(float4*)&out[idx] = o;
}

// ---------------- LSTM cell part 1: cy = sigma(f)*c + sigma(i)*tanh(g) ----------------
__global__ __launch_bounds__(256) void cell1_k(
    const float* __restrict__ gates, const float* __restrict__ cin,
    float* __restrict__ cout, int rows, int hasC)
{
  size_t gid = (size_t)blockIdx.x * 256 + threadIdx.x;
  if (gid >= (size_t)rows * HID) return;
  size_t row = gid >> 9;
  int    col = (int)(gid & (HID - 1));
  const float* g = &gates[row * G4];
  float ig = sigmoidf_(g[col]);
  float gg = tanhf(g[2 * HID + col]);
  float c;
  if (hasC) {
    float fg = sigmoidf_(g[HID + col]);
    c = fg * cin[gid] + ig * gg;
  } else {
    c = ig * gg;
  }
  cout[gid] = c;
}

// ---------------- LSTM cell part 2: hy = sigma(o)*tanh(cy) ----------------
__global__ __launch_bounds__(256) void cell2_k(
    const float* __restrict__ gates, const float* __restrict__ cy,
    float* __restrict__ hy, int rows)
{
  size_t gid = (size_t)blockIdx.x * 256 + threadIdx.x;
  if (gid >= (size_t)rows * HID) return;
  size_t row = gid >> 9;
  int    col = (int)(gid & (HID - 1));
  float og = sigmoidf_(gates[row * G4 + 3 * HID + col]);
  hy[gid] = og * tanhf(cy[gid]);
}

// ---------------- output projection: out[n,p] = h[n,:] @ W[:,p] + b[p], p<12 ----------------
// one wave per row
__global__ __launch_bounds__(256) void out_k(
    const float* __restrict__ Hh, const float* __restrict__ W,
    const float* __restrict__ b, float* __restrict__ out, int rows)
{
  int wave = (int)(((size_t)blockIdx.x * 256 + threadIdx.x) >> 6);
  int lane = threadIdx.x & 63;
  if (wave >= rows) return;
  const float* hr = &Hh[(size_t)wave * HID];
  float acc[12] = {};
  for (int k = lane; k < HID; k += 64) {
    float hv = hr[k];
    const float* wr = &W[k * 12];
    #pragma unroll
    for (int p = 0; p < 12; p++) acc[p] = fmaf(hv, wr[p], acc[p]);
  }
  #pragma unroll
  for (int p = 0; p < 12; p++) {
    float v = acc[p];
    #pragma unroll
    for (int off = 32; off > 0; off >>= 1) v += __shfl_down(v, off);
    if (lane == 0) out[(size_t)wave * 12 + p] = v + b[p];
  }
}

extern "C" void kernel_launch(void* const* d_in, const int* in_sizes, int n_in,
                              void* d_out, int out_size, void* d_ws, size_t ws_size,
                              hipStream_t stream) {
  const float* x     = (const float*)d_in[0];
  const int*   ei    = (const int*)d_in[1];
  const float* ew    = (const float*)d_in[2];
  const float* gcn0W = (const float*)d_in[3];
  // d_in[4] gcn0_b: absorbed by train-mode BN (per-column constant removed by mean)
  const float* gcnW  = (const float*)d_in[5];
  // d_in[6] gcn_b: absorbed by BN
  const float* gamma = (const float*)d_in[7];
  const float* beta  = (const float*)d_in[8];
  const float* wih   = (const float*)d_in[9];
  const float* whh   = (const float*)d_in[10];
  const float* wch   = (const float*)d_in[11];
  const float* lstmb = (const float*)d_in[12];
  const float* outW  = (const float*)d_in[13];
  const float* outb  = (const float*)d_in[14];
  float* out = (float*)d_out;

  const int* src = ei;
  const int* dst = ei + N_EDGES;

  // Workspace: 3 rotating [N,512] buffers + stats. Total 3*NH+1024 floats (~123 MB).
  float* ws = (float*)d_ws;
  const size_t NH = (size_t)N_NODES * HID;
  float* buf0  = ws;
  float* buf1  = ws + NH;
  float* buf2  = ws + 2 * NH;
  float* stats = ws + 3 * NH;   // 1024 floats

  const dim3 blk(256);
  auto gemm = [&](const float* A, const float* B, float* C, const float* bias,
                  int M, int K, int NC, int lda, int ldb, int ldc, int acc) {
    dim3 grid((M + 63) / 64, NC / 64);
    hipLaunchKernelGGL(gemm_k, grid, blk, 0, stream, A, B, C, bias,
                       M, K, NC, lda, ldb, ldc, acc);
  };
  auto zero = [&](float* p, size_t n) {
    hipLaunchKernelGGL(zero_k, dim3((unsigned)((n / 4 + 255) / 256)), blk, 0, stream, p, n);
  };

  const int ew_blocks = (N_EDGES * 128 + 255) / 256;

  // ---------------- GCN stack (3 rotating buffers; BN+ReLU in place) ----------------
  const float* gW[3] = {gcn0W, gcnW, gcnW + (size_t)HID * HID};
  const int    gK[3] = {IN_CH, HID, HID};
  const float* Ain = x;           // layer input
  float* rot[3] = {buf0, buf1, buf2};
  int xwi = 0, dsti = 1;          // buffer roles this layer
  float* h_final = nullptr;
  for (int l = 0; l < 3; l++) {
    float* XW  = rot[xwi];
    float* Hd  = rot[dsti];
    gemm(Ain, gW[l], XW, nullptr, N_NODES, gK[l], HID, gK[l], HID, HID, 0);
    zero(Hd, NH);
    hipLaunchKernelGGL(scatter_k, dim3(ew_blocks), blk, 0, stream, XW, src, dst, ew, Hd);
    zero(stats, 2 * HID);
    hipLaunchKernelGGL(bn_stats_k, dim3(8, 64), blk, 0, stream, Hd, stats, N_NODES);
    hipLaunchKernelGGL(bn_apply_k, dim3((unsigned)(NH / 4 / 256)), blk, 0, stream,
                       Hd, stats, gamma + l * HID, beta + l * HID, Hd, N_NODES);
    // rotate: Hd becomes next input; XW buffer and the old input buffer are free
    Ain = Hd;
    h_final = Hd;
    int freed = 3 - xwi - dsti;   // the buffer not used this layer (old input or spare)
    xwi = (l == 0) ? dsti : xwi;  // placeholder, recomputed below
    // simple rotation: next XW = previously-free buffer, next dst = previous XW
    xwi = freed;
    dsti = (Hd == buf0) ? ((freed == 1) ? 2 : 1) : -1;  // unused; recompute cleanly:
    // Recompute roles cleanly: input = Hd; pick any two distinct others.
    {
      int inIdx = (Hd == buf0) ? 0 : (Hd == buf1) ? 1 : 2;
      xwi  = (inIdx + 1) % 3;
      dsti = (inIdx + 2) % 3;
    }
  }

  // After GCN: h_final holds h [N,512]; the other two buffers are free.
  float* freeA = (h_final == buf0) ? buf1 : buf0;
  float* freeB = (h_final == buf2) ? ((h_final == buf0) ? buf2 : buf1) : buf2;
  if (freeB == h_final || freeB == freeA) freeB = (h_final == buf1) ? buf2 : buf1;
  // (freeA, freeB are the two buffers != h_final)

  const float* wih1 = wih + (size_t)HID * G4;
  const float* whh1 = whh + (size_t)HID * G4;
  const float* wch1 = wch + (size_t)HID * 3 * HID;

  // ---------------- LSTM + output, chunked over rows ----------------
  // Per chunk: gates = freeA (CH*2048 = NH floats exactly), c/hy in freeB.
  float* gates = freeA;
  for (int r0 = 0; r0 < N_NODES; r0 += CH) {
    const float* h_c = h_final + (size_t)r0 * HID;
    float* cbuf = freeB;                       // CH*512
    float* hbuf = freeB + (size_t)CH * HID;    // CH*512
    const int cell_blocks = (int)(((size_t)CH * HID + 255) / 256);

    // ----- layer 0 (h=c=0): gates = h @ Wih0 + b0
    gemm(h_c, wih, gates, lstmb, CH, HID, G4, HID, G4, G4, 0);
    hipLaunchKernelGGL(cell1_k, dim3(cell_blocks), blk, 0, stream,
                       gates, (const float*)nullptr, cbuf, CH, 0);
    // o peephole: gates[:,3H:] += c @ Wch0[:,2H:3H]
    gemm(cbuf, wch + 2 * HID, gates + 3 * HID, nullptr, CH, HID, HID, HID, 3 * HID, G4, 1);
    hipLaunchKernelGGL(cell2_k, dim3(cell_blocks), blk, 0, stream, gates, cbuf, hbuf, CH);

    // ----- layer 1
    gemm(h_c,  wih1, gates, lstmb + G4, CH, HID, G4, HID, G4, G4, 0);
    gemm(hbuf, whh1, gates, nullptr,    CH, HID, G4, HID, G4, G4, 1);
    // g peephole: gates[:,2H:3H] += c @ Wch1[:,0:H]
    gemm(cbuf, wch1,          gates + 2 * HID, nullptr, CH, HID, HID, HID, 3 * HID, G4, 1);
    // f peephole: gates[:,H:2H] += c @ Wch1[:,H:2H]
    gemm(cbuf, wch1 + HID,    gates + HID,     nullptr, CH, HID, HID, HID, 3 * HID, G4, 1);
    hipLaunchKernelGGL(cell1_k, dim3(cell_blocks), blk, 0, stream, gates, cbuf, cbuf, CH, 1);
    // o peephole: gates[:,3H:] += c1 @ Wch1[:,2H:3H]
    gemm(cbuf, wch1 + 2 * HID, gates + 3 * HID, nullptr, CH, HID, HID, HID, 3 * HID, G4, 1);
    hipLaunchKernelGGL(cell2_k, dim3(cell_blocks), blk, 0, stream, gates, cbuf, hbuf, CH);

    // ----- output projection for this chunk
    hipLaunchKernelGGL(out_k, dim3((CH * 64 + 255) / 256), blk, 0, stream,
                       hbuf, outW, outb, out + (size_t)r0 * 12, CH);
  }
}

// Round 3
// 4147.527 us; speedup vs baseline: 2.4978x; 2.4978x over previous
//
#include <hip/hip_runtime.h>
#include <cstddef>

#define N_NODES 20000
#define N_EDGES 320000
#define IN_CH   64
#define HID     512
#define G4      2048
#define CH      5000          // LSTM row-chunk (4 chunks); CH*G4 == N_NODES*HID exactly
#define BN_EPS  1e-5f

__device__ __forceinline__ float sigmoidf_(float x) {
  return 1.0f / (1.0f + expf(-x));
}

// ---------------- zero fill (graph-capture-safe) ----------------
__global__ __launch_bounds__(256) void zero_k(float* __restrict__ p, size_t n) {
  size_t i = ((size_t)blockIdx.x * 256 + threadIdx.x) * 4;
  if (i + 3 < n) {
    *(float4*)&p[i] = make_float4(0.f, 0.f, 0.f, 0.f);
  } else {
    for (; i < n; i++) p[i] = 0.f;
  }
}

// ---------------- CSR build: histogram over dst ----------------
__global__ __launch_bounds__(256) void hist_k(const int* __restrict__ dst,
                                              int* __restrict__ counts) {
  int e = blockIdx.x * 256 + threadIdx.x;
  if (e < N_EDGES) atomicAdd(&counts[dst[e]], 1);
}

// ---------------- CSR build: exclusive scan (single block, 1024 thr) ----------------
__global__ __launch_bounds__(1024) void scan_k(const int* __restrict__ counts,
                                               int* __restrict__ offsets,
                                               int* __restrict__ pos, int n) {
  __shared__ int tmp[1024];
  __shared__ int carry_s;
  const int tid = threadIdx.x;
  if (tid == 0) carry_s = 0;
  __syncthreads();
  for (int base = 0; base < n; base += 1024) {
    int i = base + tid;
    int v = (i < n) ? counts[i] : 0;
    tmp[tid] = v;
    __syncthreads();
    #pragma unroll
    for (int off = 1; off < 1024; off <<= 1) {
      int t = (tid >= off) ? tmp[tid - off] : 0;
      __syncthreads();
      tmp[tid] += t;
      __syncthreads();
    }
    if (i < n) {
      int excl = carry_s + tmp[tid] - v;
      offsets[i] = excl;
      pos[i] = excl;
    }
    __syncthreads();
    if (tid == 1023) carry_s += tmp[1023];
    __syncthreads();
  }
  if (tid == 0) offsets[n] = carry_s;
}

// ---------------- CSR build: bucket fill ----------------
__global__ __launch_bounds__(256) void fill_k(
    const int* __restrict__ src, const int* __restrict__ dst,
    const float* __restrict__ ew, int* __restrict__ pos,
    int* __restrict__ s_s, float* __restrict__ w_s) {
  int e = blockIdx.x * 256 + threadIdx.x;
  if (e >= N_EDGES) return;
  int p = atomicAdd(&pos[dst[e]], 1);
  s_s[p] = src[e];
  w_s[p] = ew[e];
}

// ---------------- aggregation gather: H[n,:] = sum_{e in in(n)} w_e * XW[src_e,:] ----
// one block (128 thr) per node; thread t owns float4 cols [4t,4t+4)
__global__ __launch_bounds__(128) void gather_k(
    const float* __restrict__ XW, const int* __restrict__ offsets,
    const int* __restrict__ s_s, const float* __restrict__ w_s,
    float* __restrict__ H) {
  const int n = blockIdx.x;
  const int t = threadIdx.x;
  const int beg = offsets[n], end = offsets[n + 1];
  float4 acc = make_float4(0.f, 0.f, 0.f, 0.f);
  for (int i = beg; i < end; i++) {
    const int   s = s_s[i];
    const float w = w_s[i];
    const float4 v = *(const float4*)&XW[(size_t)s * HID + t * 4];
    acc.x = fmaf(w, v.x, acc.x);
    acc.y = fmaf(w, v.y, acc.y);
    acc.z = fmaf(w, v.z, acc.z);
    acc.w = fmaf(w, v.w, acc.w);
  }
  *(float4*)&H[(size_t)n * HID + t * 4] = acc;
}

// ---------------- GEMM: C[M,NC] (+)= A[M,K] @ B[K,NC] (+ bias) ----------------
__global__ __launch_bounds__(256) void gemm_k(
    const float* __restrict__ A, const float* __restrict__ B,
    float* __restrict__ C, const float* __restrict__ bias,
    int M, int K, int NC, int lda, int ldb, int ldc, int acc)
{
  __shared__ float As[16][68];
  __shared__ float Bs[16][64];
  const int row0 = blockIdx.x * 64;
  const int col0 = blockIdx.y * 64;
  const int t  = threadIdx.x;
  const int tx = t & 15, ty = t >> 4;
  float accr[4][4] = {};
  for (int k0 = 0; k0 < K; k0 += 16) {
    #pragma unroll
    for (int i = 0; i < 4; i++) {
      int idx = t + i * 256;
      int r = idx >> 4, c = idx & 15;
      int gr = row0 + r;
      As[c][r] = (gr < M) ? A[(size_t)gr * lda + (k0 + c)] : 0.0f;
    }
    #pragma unroll
    for (int i = 0; i < 4; i++) {
      int idx = t + i * 256;
      int r = idx >> 6, c = idx & 63;
      Bs[r][c] = B[(size_t)(k0 + r) * ldb + (col0 + c)];
    }
    __syncthreads();
    #pragma unroll
    for (int kk = 0; kk < 16; kk++) {
      const float4 a4 = *(const float4*)&As[kk][ty * 4];
      const float4 b4 = *(const float4*)&Bs[kk][tx * 4];
      const float a[4] = {a4.x, a4.y, a4.z, a4.w};
      const float b[4] = {b4.x, b4.y, b4.z, b4.w};
      #pragma unroll
      for (int m = 0; m < 4; m++)
        #pragma unroll
        for (int n = 0; n < 4; n++)
          accr[m][n] = fmaf(a[m], b[n], accr[m][n]);
    }
    __syncthreads();
  }
  #pragma unroll
  for (int m = 0; m < 4; m++) {
    int gr = row0 + ty * 4 + m;
    if (gr >= M) continue;
    float* cp = &C[(size_t)gr * ldc + col0 + tx * 4];
    float4 o;
    if (acc)       o = *(const float4*)cp;
    else if (bias) o = *(const float4*)&bias[col0 + tx * 4];
    else           o = make_float4(0.f, 0.f, 0.f, 0.f);
    o.x += accr[m][0]; o.y += accr[m][1]; o.z += accr[m][2]; o.w += accr[m][3];
    *(float4*)cp = o;
  }
}

// ---------------- BN stats ----------------
__global__ __launch_bounds__(256) void bn_stats_k(
    const float* __restrict__ H, float* __restrict__ stats, int N)
{
  const int tx = threadIdx.x & 63;
  const int ty = threadIdx.x >> 6;
  const int col = blockIdx.x * 64 + tx;
  float s1 = 0.f, s2 = 0.f;
  for (int r = blockIdx.y * 4 + ty; r < N; r += gridDim.y * 4) {
    float v = H[(size_t)r * HID + col];
    s1 += v; s2 += v * v;
  }
  __shared__ float red[2][4][64];
  red[0][ty][tx] = s1;
  red[1][ty][tx] = s2;
  __syncthreads();
  if (ty == 0) {
    s1 = red[0][0][tx] + red[0][1][tx] + red[0][2][tx] + red[0][3][tx];
    s2 = red[1][0][tx] + red[1][1][tx] + red[1][2][tx] + red[1][3][tx];
    atomicAdd(&stats[col], s1);
    atomicAdd(&stats[HID + col], s2);
  }
}

// ---------------- BN apply + ReLU (in-place safe) ----------------
__global__ __launch_bounds__(256) void bn_apply_k(
    const float* __restrict__ H, const float* __restrict__ stats,
    const float* __restrict__ gamma, const float* __restrict__ beta,
    float* __restrict__ out, int N)
{
  size_t gid = (size_t)blockIdx.x * 256 + threadIdx.x;
  size_t idx = gid * 4;
  if (idx >= (size_t)N * HID) return;
  int col = (int)(idx & (HID - 1));
  const float4 v = *(const float4*)&H[idx];
  float r[4] = {v.x, v.y, v.z, v.w};
  float4 o;
  float* op = &o.x;
  #pragma unroll
  for (int i = 0; i < 4; i++) {
    int c = col + i;
    float mean = stats[c] * (1.0f / N);
    float var  = stats[HID + c] * (1.0f / N) - mean * mean;
    float scale = gamma[c] / sqrtf(var + BN_EPS);
    float shift = beta[c] - mean * scale;
    op[i] = fmaxf(fmaf(r[i], scale, shift), 0.0f);
  }
  *(float4*)&out[idx] = o;
}

// ---------------- LSTM cell part 1 ----------------
__global__ __launch_bounds__(256) void cell1_k(
    const float* __restrict__ gates, const float* __restrict__ cin,
    float* __restrict__ cout, int rows, int hasC)
{
  size_t gid = (size_t)blockIdx.x * 256 + threadIdx.x;
  if (gid >= (size_t)rows * HID) return;
  size_t row = gid >> 9;
  int    col = (int)(gid & (HID - 1));
  const float* g = &gates[row * G4];
  float ig = sigmoidf_(g[col]);
  float gg = tanhf(g[2 * HID + col]);
  float c;
  if (hasC) {
    float fg = sigmoidf_(g[HID + col]);
    c = fg * cin[gid] + ig * gg;
  } else {
    c = ig * gg;
  }
  cout[gid] = c;
}

// ---------------- LSTM cell part 2 ----------------
__global__ __launch_bounds__(256) void cell2_k(
    const float* __restrict__ gates, const float* __restrict__ cy,
    float* __restrict__ hy, int rows)
{
  size_t gid = (size_t)blockIdx.x * 256 + threadIdx.x;
  if (gid >= (size_t)rows * HID) return;
  size_t row = gid >> 9;
  int    col = (int)(gid & (HID - 1));
  float og = sigmoidf_(gates[row * G4 + 3 * HID + col]);
  hy[gid] = og * tanhf(cy[gid]);
}

// ---------------- output projection ----------------
__global__ __launch_bounds__(256) void out_k(
    const float* __restrict__ Hh, const float* __restrict__ W,
    const float* __restrict__ b, float* __restrict__ out, int rows)
{
  int wave = (int)(((size_t)blockIdx.x * 256 + threadIdx.x) >> 6);
  int lane = threadIdx.x & 63;
  if (wave >= rows) return;
  const float* hr = &Hh[(size_t)wave * HID];
  float acc[12] = {};
  for (int k = lane; k < HID; k += 64) {
    float hv = hr[k];
    const float* wr = &W[k * 12];
    #pragma unroll
    for (int p = 0; p < 12; p++) acc[p] = fmaf(hv, wr[p], acc[p]);
  }
  #pragma unroll
  for (int p = 0; p < 12; p++) {
    float v = acc[p];
    #pragma unroll
    for (int off = 32; off > 0; off >>= 1) v += __shfl_down(v, off);
    if (lane == 0) out[(size_t)wave * 12 + p] = v + b[p];
  }
}

extern "C" void kernel_launch(void* const* d_in, const int* in_sizes, int n_in,
                              void* d_out, int out_size, void* d_ws, size_t ws_size,
                              hipStream_t stream) {
  const float* x     = (const float*)d_in[0];
  const int*   ei    = (const int*)d_in[1];
  const float* ew    = (const float*)d_in[2];
  const float* gcn0W = (const float*)d_in[3];
  // d_in[4] gcn0_b: absorbed by train-mode BN
  const float* gcnW  = (const float*)d_in[5];
  // d_in[6] gcn_b: absorbed by BN
  const float* gamma = (const float*)d_in[7];
  const float* beta  = (const float*)d_in[8];
  const float* wih   = (const float*)d_in[9];
  const float* whh   = (const float*)d_in[10];
  const float* wch   = (const float*)d_in[11];
  const float* lstmb = (const float*)d_in[12];
  const float* outW  = (const float*)d_in[13];
  const float* outb  = (const float*)d_in[14];
  float* out = (float*)d_out;

  const int* src = ei;
  const int* dst = ei + N_EDGES;

  // Workspace layout (floats): buf0|buf1|buf2 (N*512 each) | stats(1024) | CSR ints
  float* ws = (float*)d_ws;
  const size_t NH = (size_t)N_NODES * HID;
  float* buf0  = ws;
  float* buf1  = ws + NH;
  float* buf2  = ws + 2 * NH;
  float* stats = ws + 3 * NH;               // 1024 floats
  int*   csr   = (int*)(ws + 3 * NH + 1024);
  int*   counts  = csr;                     // [20000]
  int*   offsets = csr + 20032;             // [20001]
  int*   cpos    = csr + 40064;             // [20000]
  int*   s_s     = csr + 60096;             // [320000]
  float* w_s     = (float*)(csr + 380096);  // [320000]
  // total ws use: 3*NH + 1024 + 700096 floats ≈ 125.7 MB

  const dim3 blk(256);
  auto gemm = [&](const float* A, const float* B, float* C, const float* bias,
                  int M, int K, int NC, int lda, int ldb, int ldc, int acc) {
    dim3 grid((M + 63) / 64, NC / 64);
    hipLaunchKernelGGL(gemm_k, grid, blk, 0, stream, A, B, C, bias,
                       M, K, NC, lda, ldb, ldc, acc);
  };
  auto zero = [&](float* p, size_t n) {
    hipLaunchKernelGGL(zero_k, dim3((unsigned)((n / 4 + 255) / 256)), blk, 0, stream, p, n);
  };

  const int e_blocks = (N_EDGES + 255) / 256;

  // ---------------- build CSR by dst (once; reused by all 3 GCN layers) ----------
  zero((float*)counts, N_NODES);
  hipLaunchKernelGGL(hist_k, dim3(e_blocks), blk, 0, stream, dst, counts);
  hipLaunchKernelGGL(scan_k, dim3(1), dim3(1024), 0, stream, counts, offsets, cpos, N_NODES);
  hipLaunchKernelGGL(fill_k, dim3(e_blocks), blk, 0, stream, src, dst, ew, cpos, s_s, w_s);

  // ---------------- GCN stack ----------------
  // L0: A=x    XW=buf0  H=buf1
  // L1: A=buf1 XW=buf0  H=buf2
  // L2: A=buf2 XW=buf0  H=buf1   -> h_final = buf1
  const float* gW[3]  = {gcn0W, gcnW, gcnW + (size_t)HID * HID};
  const int    gK[3]  = {IN_CH, HID, HID};
  const float* gA[3]  = {x, buf1, buf2};
  float*       gH[3]  = {buf1, buf2, buf1};
  for (int l = 0; l < 3; l++) {
    gemm(gA[l], gW[l], buf0, nullptr, N_NODES, gK[l], HID, gK[l], HID, HID, 0);
    hipLaunchKernelGGL(gather_k, dim3(N_NODES), dim3(128), 0, stream,
                       buf0, offsets, s_s, w_s, gH[l]);
    zero(stats, 2 * HID);
    hipLaunchKernelGGL(bn_stats_k, dim3(8, 64), blk, 0, stream, gH[l], stats, N_NODES);
    hipLaunchKernelGGL(bn_apply_k, dim3((unsigned)(NH / 4 / 256)), blk, 0, stream,
                       gH[l], stats, gamma + l * HID, beta + l * HID, gH[l], N_NODES);
  }
  float* h_final = buf1;
  float* gates   = buf0;   // CH*2048 = NH floats exactly
  float* cbuf    = buf2;                     // CH*512
  float* hbuf    = buf2 + (size_t)CH * HID;  // CH*512

  const float* wih1 = wih + (size_t)HID * G4;
  const float* whh1 = whh + (size_t)HID * G4;
  const float* wch1 = wch + (size_t)HID * 3 * HID;

  // ---------------- LSTM + output, chunked over rows ----------------
  for (int r0 = 0; r0 < N_NODES; r0 += CH) {
    const float* h_c = h_final + (size_t)r0 * HID;
    const int cell_blocks = (int)(((size_t)CH * HID + 255) / 256);

    // ----- layer 0 (h=c=0)
    gemm(h_c, wih, gates, lstmb, CH, HID, G4, HID, G4, G4, 0);
    hipLaunchKernelGGL(cell1_k, dim3(cell_blocks), blk, 0, stream,
                       gates, (const float*)nullptr, cbuf, CH, 0);
    gemm(cbuf, wch + 2 * HID, gates + 3 * HID, nullptr, CH, HID, HID, HID, 3 * HID, G4, 1);
    hipLaunchKernelGGL(cell2_k, dim3(cell_blocks), blk, 0, stream, gates, cbuf, hbuf, CH);

    // ----- layer 1
    gemm(h_c,  wih1, gates, lstmb + G4, CH, HID, G4, HID, G4, G4, 0);
    gemm(hbuf, whh1, gates, nullptr,    CH, HID, G4, HID, G4, G4, 1);
    gemm(cbuf, wch1,          gates + 2 * HID, nullptr, CH, HID, HID, HID, 3 * HID, G4, 1);
    gemm(cbuf, wch1 + HID,    gates + HID,     nullptr, CH, HID, HID, HID, 3 * HID, G4, 1);
    hipLaunchKernelGGL(cell1_k, dim3(cell_blocks), blk, 0, stream, gates, cbuf, cbuf, CH, 1);
    gemm(cbuf, wch1 + 2 * HID, gates + 3 * HID, nullptr, CH, HID, HID, HID, 3 * HID, G4, 1);
    hipLaunchKernelGGL(cell2_k, dim3(cell_blocks), blk, 0, stream, gates, cbuf, hbuf, CH);

    // ----- output projection for this chunk
    hipLaunchKernelGGL(out_k, dim3((CH * 64 + 255) / 256), blk, 0, stream,
                       hbuf, outW, outb, out + (size_t)r0 * 12, CH);
  }
}

// Round 4
// 1553.882 us; speedup vs baseline: 6.6671x; 2.6691x over previous
//
#include <hip/hip_runtime.h>
#include <cstddef>

#define N_NODES 20000
#define N_EDGES 320000
#define IN_CH   64
#define HID     512
#define G4      2048
#define CH      5000
#define BN_EPS  1e-5f

typedef __attribute__((ext_vector_type(8))) short short8;
typedef __attribute__((ext_vector_type(4))) float f32x4;

__device__ __forceinline__ float sigmoidf_(float x) {
  return 1.0f / (1.0f + expf(-x));
}

// fp32 -> bf16 (RNE)
__device__ __forceinline__ unsigned short f2b(float f) {
  unsigned int u = __float_as_uint(f);
  u += 0x7FFFu + ((u >> 16) & 1u);
  return (unsigned short)(u >> 16);
}

__device__ __forceinline__ f32x4 mfma_bf16(short8 a, short8 b, f32x4 c) {
  asm volatile("v_mfma_f32_16x16x32_bf16 %0, %1, %2, %0"
               : "+v"(c) : "v"(a), "v"(b));
  return c;
}

// async 16B global->LDS (wave-uniform LDS base + lane*16)
__device__ __forceinline__ void gld_lds16(const unsigned short* g, unsigned short* l) {
  __builtin_amdgcn_global_load_lds(
      (const __attribute__((address_space(1))) unsigned int*)(const void*)g,
      (__attribute__((address_space(3))) unsigned int*)(void*)l, 16, 0, 0);
}

// ---------------- zero fill ----------------
__global__ __launch_bounds__(256) void zero_k(float* __restrict__ p, size_t n) {
  size_t i = ((size_t)blockIdx.x * 256 + threadIdx.x) * 4;
  if (i + 3 < n) {
    *(float4*)&p[i] = make_float4(0.f, 0.f, 0.f, 0.f);
  } else {
    for (; i < n; i++) p[i] = 0.f;
  }
}

// ---------------- elementwise f32 -> bf16 ----------------
__global__ __launch_bounds__(256) void cvt_k(const float* __restrict__ in,
                                             unsigned short* __restrict__ out, size_t n) {
  size_t i = ((size_t)blockIdx.x * 256 + threadIdx.x) * 4;
  if (i + 3 < n) {
    const float4 v = *(const float4*)&in[i];
    ushort4 o; o.x = f2b(v.x); o.y = f2b(v.y); o.z = f2b(v.z); o.w = f2b(v.w);
    *(ushort4*)&out[i] = o;
  } else {
    for (; i < n; i++) out[i] = f2b(in[i]);
  }
}

// ---------------- fused transpose + cvt: Wt[n][k] = bf16(W[k][n0+n]) ----------------
__global__ void tcvt_k(const float* __restrict__ W, unsigned short* __restrict__ Wt,
                       int K, int NC, int ldw) {
  __shared__ float tile[32][33];
  const int n0 = blockIdx.x * 32, k0 = blockIdx.y * 32;
  const int tx = threadIdx.x, ty = threadIdx.y;  // 32 x 8
  #pragma unroll
  for (int i = 0; i < 32; i += 8) {
    int k = k0 + ty + i, n = n0 + tx;
    tile[ty + i][tx] = (k < K && n < NC) ? W[(size_t)k * ldw + n] : 0.f;
  }
  __syncthreads();
  #pragma unroll
  for (int i = 0; i < 32; i += 8) {
    int n = n0 + ty + i, k = k0 + tx;
    if (n < NC && k < K) Wt[(size_t)n * K + k] = f2b(tile[tx][ty + i]);
  }
}

// ---------------- CSR build ----------------
__global__ __launch_bounds__(256) void hist_k(const int* __restrict__ dst,
                                              int* __restrict__ counts) {
  int e = blockIdx.x * 256 + threadIdx.x;
  if (e < N_EDGES) atomicAdd(&counts[dst[e]], 1);
}

__global__ __launch_bounds__(1024) void scan_k(const int* __restrict__ counts,
                                               int* __restrict__ offsets,
                                               int* __restrict__ pos, int n) {
  __shared__ int tmp[1024];
  __shared__ int carry_s;
  const int tid = threadIdx.x;
  if (tid == 0) carry_s = 0;
  __syncthreads();
  for (int base = 0; base < n; base += 1024) {
    int i = base + tid;
    int v = (i < n) ? counts[i] : 0;
    tmp[tid] = v;
    __syncthreads();
    #pragma unroll
    for (int off = 1; off < 1024; off <<= 1) {
      int t = (tid >= off) ? tmp[tid - off] : 0;
      __syncthreads();
      tmp[tid] += t;
      __syncthreads();
    }
    if (i < n) {
      int excl = carry_s + tmp[tid] - v;
      offsets[i] = excl;
      pos[i] = excl;
    }
    __syncthreads();
    if (tid == 1023) carry_s += tmp[1023];
    __syncthreads();
  }
  if (tid == 0) offsets[n] = carry_s;
}

__global__ __launch_bounds__(256) void fill_k(
    const int* __restrict__ src, const int* __restrict__ dst,
    const float* __restrict__ ew, int* __restrict__ pos,
    int* __restrict__ s_s, float* __restrict__ w_s) {
  int e = blockIdx.x * 256 + threadIdx.x;
  if (e >= N_EDGES) return;
  int p = atomicAdd(&pos[dst[e]], 1);
  s_s[p] = src[e];
  w_s[p] = ew[e];
}

// ---------------- aggregation gather ----------------
__global__ __launch_bounds__(128) void gather_k(
    const float* __restrict__ XW, const int* __restrict__ offsets,
    const int* __restrict__ s_s, const float* __restrict__ w_s,
    float* __restrict__ H) {
  const int n = blockIdx.x;
  const int t = threadIdx.x;
  const int beg = offsets[n], end = offsets[n + 1];
  float4 acc = make_float4(0.f, 0.f, 0.f, 0.f);
  for (int i = beg; i < end; i++) {
    const int   s = s_s[i];
    const float w = w_s[i];
    const float4 v = *(const float4*)&XW[(size_t)s * HID + t * 4];
    acc.x = fmaf(w, v.x, acc.x);
    acc.y = fmaf(w, v.y, acc.y);
    acc.z = fmaf(w, v.z, acc.z);
    acc.w = fmaf(w, v.w, acc.w);
  }
  *(float4*)&H[(size_t)n * HID + t * 4] = acc;
}

// ---------------- bf16 MFMA GEMM ----------------
// C[M,NC](f32, ldc) (+)= A[M,K](bf16 row-major) * Bt[NC,K](bf16 row-major)^T (+bias)
// 128x128 tile, BK=32, 256 thr (4 waves, each 64x64). NC%128==0, K%32==0.
__global__ __launch_bounds__(256) void gemm_bf16_k(
    const unsigned short* __restrict__ A, const unsigned short* __restrict__ Bt,
    float* __restrict__ C, const float* __restrict__ bias,
    int M, int K, int NC, int ldc, int acc)
{
  __shared__ unsigned short As[128 * 32];
  __shared__ unsigned short Bs[128 * 32];
  const int row0 = blockIdx.x * 128;
  const int col0 = blockIdx.y * 128;
  const int t    = threadIdx.x;
  const int lane = t & 63;
  const int w    = t >> 6;
  const int wr   = w >> 1, wc = w & 1;
  const int q    = lane >> 4;
  const int l16  = lane & 15;

  f32x4 accr[4][4] = {};

  for (int k0 = 0; k0 < K; k0 += 32) {
    // stage A tile (128 rows x 32 bf16 = 512 x 16B chunks), chunk c -> LDS byte c*16
    #pragma unroll
    for (int i = 0; i < 2; i++) {
      int c  = w * 64 + lane + i * 256;
      int r  = c >> 2, kq = c & 3;
      int gr = row0 + r; if (gr > M - 1) gr = M - 1;   // clamp; OOB rows never stored
      gld_lds16(A + (size_t)gr * K + k0 + kq * 8, As + (size_t)(w * 64 + i * 256) * 8);
    }
    #pragma unroll
    for (int i = 0; i < 2; i++) {
      int c = w * 64 + lane + i * 256;
      int r = c >> 2, kq = c & 3;
      gld_lds16(Bt + (size_t)(col0 + r) * K + k0 + kq * 8, Bs + (size_t)(w * 64 + i * 256) * 8);
    }
    __syncthreads();   // compiler drains vmcnt before s_barrier

    short8 af[4], bf[4];
    #pragma unroll
    for (int mi = 0; mi < 4; mi++)
      af[mi] = *(const short8*)&As[(wr * 64 + mi * 16 + l16) * 32 + q * 8];
    #pragma unroll
    for (int ni = 0; ni < 4; ni++)
      bf[ni] = *(const short8*)&Bs[(wc * 64 + ni * 16 + l16) * 32 + q * 8];
    #pragma unroll
    for (int mi = 0; mi < 4; mi++)
      #pragma unroll
      for (int ni = 0; ni < 4; ni++)
        accr[mi][ni] = mfma_bf16(af[mi], bf[ni], accr[mi][ni]);
    __syncthreads();
  }

  // epilogue: C/D layout col=lane&15, row=(lane>>4)*4+reg
  #pragma unroll
  for (int mi = 0; mi < 4; mi++) {
    #pragma unroll
    for (int ni = 0; ni < 4; ni++) {
      int col = col0 + wc * 64 + ni * 16 + l16;
      #pragma unroll
      for (int r = 0; r < 4; r++) {
        int row = row0 + wr * 64 + mi * 16 + q * 4 + r;
        if (row < M) {
          float v = accr[mi][ni][r];
          float* cp = &C[(size_t)row * ldc + col];
          if (acc)       *cp += v;
          else if (bias) *cp  = v + bias[col];
          else           *cp  = v;
        }
      }
    }
  }
}

// ---------------- BN stats ----------------
__global__ __launch_bounds__(256) void bn_stats_k(
    const float* __restrict__ H, float* __restrict__ stats, int N)
{
  const int tx = threadIdx.x & 63;
  const int ty = threadIdx.x >> 6;
  const int col = blockIdx.x * 64 + tx;
  float s1 = 0.f, s2 = 0.f;
  for (int r = blockIdx.y * 4 + ty; r < N; r += gridDim.y * 4) {
    float v = H[(size_t)r * HID + col];
    s1 += v; s2 += v * v;
  }
  __shared__ float red[2][4][64];
  red[0][ty][tx] = s1;
  red[1][ty][tx] = s2;
  __syncthreads();
  if (ty == 0) {
    s1 = red[0][0][tx] + red[0][1][tx] + red[0][2][tx] + red[0][3][tx];
    s2 = red[1][0][tx] + red[1][1][tx] + red[1][2][tx] + red[1][3][tx];
    atomicAdd(&stats[col], s1);
    atomicAdd(&stats[HID + col], s2);
  }
}

// ---------------- BN apply + ReLU -> bf16 ----------------
__global__ __launch_bounds__(256) void bn_apply_k(
    const float* __restrict__ H, const float* __restrict__ stats,
    const float* __restrict__ gamma, const float* __restrict__ beta,
    unsigned short* __restrict__ out, int N)
{
  size_t gid = (size_t)blockIdx.x * 256 + threadIdx.x;
  size_t idx = gid * 4;
  if (idx >= (size_t)N * HID) return;
  int col = (int)(idx & (HID - 1));
  const float4 v = *(const float4*)&H[idx];
  float r[4] = {v.x, v.y, v.z, v.w};
  ushort4 o;
  unsigned short* op = &o.x;
  #pragma unroll
  for (int i = 0; i < 4; i++) {
    int c = col + i;
    float mean = stats[c] * (1.0f / N);
    float var  = stats[HID + c] * (1.0f / N) - mean * mean;
    float scale = gamma[c] / sqrtf(var + BN_EPS);
    float shift = beta[c] - mean * scale;
    op[i] = f2b(fmaxf(fmaf(r[i], scale, shift), 0.0f));
  }
  *(ushort4*)&out[idx] = o;
}

// ---------------- LSTM cell part 1 (dual-write c fp32 + bf16) ----------------
__global__ __launch_bounds__(256) void cell1_k(
    const float* __restrict__ gates, const float* __restrict__ cin,
    float* __restrict__ cout, unsigned short* __restrict__ cout16,
    int rows, int hasC)
{
  size_t gid = (size_t)blockIdx.x * 256 + threadIdx.x;
  if (gid >= (size_t)rows * HID) return;
  size_t row = gid >> 9;
  int    col = (int)(gid & (HID - 1));
  const float* g = &gates[row * G4];
  float ig = sigmoidf_(g[col]);
  float gg = tanhf(g[2 * HID + col]);
  float c;
  if (hasC) {
    float fg = sigmoidf_(g[HID + col]);
    c = fg * cin[gid] + ig * gg;
  } else {
    c = ig * gg;
  }
  cout[gid] = c;
  cout16[gid] = f2b(c);
}

// ---------------- LSTM cell part 2 (dual-write hy fp32 + bf16) ----------------
__global__ __launch_bounds__(256) void cell2_k(
    const float* __restrict__ gates, const float* __restrict__ cy,
    float* __restrict__ hy, unsigned short* __restrict__ hy16, int rows)
{
  size_t gid = (size_t)blockIdx.x * 256 + threadIdx.x;
  if (gid >= (size_t)rows * HID) return;
  size_t row = gid >> 9;
  int    col = (int)(gid & (HID - 1));
  float og = sigmoidf_(gates[row * G4 + 3 * HID + col]);
  float h = og * tanhf(cy[gid]);
  hy[gid] = h;
  hy16[gid] = f2b(h);
}

// ---------------- output projection (fp32) ----------------
__global__ __launch_bounds__(256) void out_k(
    const float* __restrict__ Hh, const float* __restrict__ W,
    const float* __restrict__ b, float* __restrict__ out, int rows)
{
  int wave = (int)(((size_t)blockIdx.x * 256 + threadIdx.x) >> 6);
  int lane = threadIdx.x & 63;
  if (wave >= rows) return;
  const float* hr = &Hh[(size_t)wave * HID];
  float acc[12] = {};
  for (int k = lane; k < HID; k += 64) {
    float hv = hr[k];
    const float* wr = &W[k * 12];
    #pragma unroll
    for (int p = 0; p < 12; p++) acc[p] = fmaf(hv, wr[p], acc[p]);
  }
  #pragma unroll
  for (int p = 0; p < 12; p++) {
    float v = acc[p];
    #pragma unroll
    for (int off = 32; off > 0; off >>= 1) v += __shfl_down(v, off);
    if (lane == 0) out[(size_t)wave * 12 + p] = v + b[p];
  }
}

extern "C" void kernel_launch(void* const* d_in, const int* in_sizes, int n_in,
                              void* d_out, int out_size, void* d_ws, size_t ws_size,
                              hipStream_t stream) {
  const float* x     = (const float*)d_in[0];
  const int*   ei    = (const int*)d_in[1];
  const float* ew    = (const float*)d_in[2];
  const float* gcn0W = (const float*)d_in[3];
  const float* gcnW  = (const float*)d_in[5];
  const float* gamma = (const float*)d_in[7];
  const float* beta  = (const float*)d_in[8];
  const float* wih   = (const float*)d_in[9];
  const float* whh   = (const float*)d_in[10];
  const float* wch   = (const float*)d_in[11];
  const float* lstmb = (const float*)d_in[12];
  const float* outW  = (const float*)d_in[13];
  const float* outb  = (const float*)d_in[14];
  float* out = (float*)d_out;

  const int* src = ei;
  const int* dst = ei + N_EDGES;

  // -------- workspace layout (~138 MB) --------
  float* ws = (float*)d_ws;
  const size_t NH = (size_t)N_NODES * HID;
  float* buf0 = ws;            // XW fp32 during GCN; gates fp32 during LSTM
  float* bufH = ws + NH;       // gather H fp32 during GCN; c/hy buffers during LSTM
  unsigned short* hbA16 = (unsigned short*)(ws + 2 * NH);   // [N,512] bf16
  unsigned short* hbB16 = hbA16 + NH;                       // [N,512] bf16
  unsigned short* x16   = hbB16 + NH;                       // [N,64]  bf16
  unsigned short* g0t   = x16 + (size_t)N_NODES * IN_CH;    // [512,64]
  unsigned short* g1t   = g0t   + 512 * 64;                 // [512,512]
  unsigned short* g2t   = g1t   + 512 * 512;
  unsigned short* wih0t = g2t   + 512 * 512;                // [2048,512]
  unsigned short* wih1t = wih0t + 2048 * 512;
  unsigned short* whh1t = wih1t + 2048 * 512;
  unsigned short* wch0ot= whh1t + 2048 * 512;               // [512,512]
  unsigned short* wch1t = wch0ot + 512 * 512;               // [1536,512]
  float* stats = (float*)(wch1t + 1536 * 512);              // 1024 floats
  int*   csr   = (int*)(stats + 1024);
  int*   counts  = csr;
  int*   offsets = csr + 20032;
  int*   cpos    = csr + 40064;
  int*   s_s     = csr + 60096;
  float* w_s     = (float*)(csr + 380096);

  // LSTM chunk overlays in bufH
  float* cbuf = bufH;
  float* hbuf = bufH + (size_t)CH * HID;
  unsigned short* cb16 = (unsigned short*)(bufH + 2 * (size_t)CH * HID);
  unsigned short* hb16 = cb16 + (size_t)CH * HID;

  const dim3 blk(256);
  auto gemm = [&](const unsigned short* A, const unsigned short* Bt, float* C,
                  const float* bias, int M, int K, int NC, int ldc, int acc) {
    dim3 grid((M + 127) / 128, NC / 128);
    hipLaunchKernelGGL(gemm_bf16_k, grid, blk, 0, stream, A, Bt, C, bias, M, K, NC, ldc, acc);
  };
  auto tcvt = [&](const float* W, unsigned short* Wt, int K, int NC, int ldw) {
    dim3 grid((NC + 31) / 32, (K + 31) / 32);
    hipLaunchKernelGGL(tcvt_k, grid, dim3(32, 8), 0, stream, W, Wt, K, NC, ldw);
  };
  auto zero = [&](float* p, size_t n) {
    hipLaunchKernelGGL(zero_k, dim3((unsigned)((n / 4 + 255) / 256)), blk, 0, stream, p, n);
  };

  // -------- weight prep (bf16 transposed) + x cvt --------
  tcvt(gcn0W, g0t, IN_CH, HID, HID);
  tcvt(gcnW,                    g1t, HID, HID, HID);
  tcvt(gcnW + (size_t)HID * HID, g2t, HID, HID, HID);
  tcvt(wih,                      wih0t, HID, G4, G4);
  tcvt(wih + (size_t)HID * G4,   wih1t, HID, G4, G4);
  tcvt(whh + (size_t)HID * G4,   whh1t, HID, G4, G4);
  tcvt(wch + 2 * HID,            wch0ot, HID, HID, 3 * HID);   // Wch0[:,2H:3H]
  tcvt(wch + (size_t)HID * 3 * HID, wch1t, HID, 3 * HID, 3 * HID);
  hipLaunchKernelGGL(cvt_k, dim3((N_NODES * IN_CH / 4 + 255) / 256), blk, 0, stream,
                     x, x16, (size_t)N_NODES * IN_CH);

  // -------- CSR build --------
  const int e_blocks = (N_EDGES + 255) / 256;
  zero((float*)counts, N_NODES);
  hipLaunchKernelGGL(hist_k, dim3(e_blocks), blk, 0, stream, dst, counts);
  hipLaunchKernelGGL(scan_k, dim3(1), dim3(1024), 0, stream, counts, offsets, cpos, N_NODES);
  hipLaunchKernelGGL(fill_k, dim3(e_blocks), blk, 0, stream, src, dst, ew, cpos, s_s, w_s);

  // -------- GCN stack --------
  const unsigned short* gWt[3] = {g0t, g1t, g2t};
  const int             gK[3]  = {IN_CH, HID, HID};
  const unsigned short* gA[3]  = {x16, hbA16, hbB16};
  unsigned short*       gO[3]  = {hbA16, hbB16, hbA16};
  for (int l = 0; l < 3; l++) {
    gemm(gA[l], gWt[l], buf0, nullptr, N_NODES, gK[l], HID, HID, 0);
    hipLaunchKernelGGL(gather_k, dim3(N_NODES), dim3(128), 0, stream,
                       buf0, offsets, s_s, w_s, bufH);
    zero(stats, 2 * HID);
    hipLaunchKernelGGL(bn_stats_k, dim3(8, 64), blk, 0, stream, bufH, stats, N_NODES);
    hipLaunchKernelGGL(bn_apply_k, dim3((unsigned)(NH / 4 / 256)), blk, 0, stream,
                       bufH, stats, gamma + l * HID, beta + l * HID, gO[l], N_NODES);
  }
  unsigned short* hfin16 = hbA16;
  float* gates = buf0;

  const unsigned short* wch1g = wch1t;                    // [:,0:H]^T
  const unsigned short* wch1f = wch1t + (size_t)HID * HID;    // [:,H:2H]^T
  const unsigned short* wch1o = wch1t + 2 * (size_t)HID * HID;// [:,2H:3H]^T

  // -------- LSTM + output, chunked --------
  for (int r0 = 0; r0 < N_NODES; r0 += CH) {
    const unsigned short* h_c = hfin16 + (size_t)r0 * HID;
    const int cell_blocks = (int)(((size_t)CH * HID + 255) / 256);

    // layer 0 (h=c=0)
    gemm(h_c, wih0t, gates, lstmb, CH, HID, G4, G4, 0);
    hipLaunchKernelGGL(cell1_k, dim3(cell_blocks), blk, 0, stream,
                       gates, (const float*)nullptr, cbuf, cb16, CH, 0);
    gemm(cb16, wch0ot, gates + 3 * HID, nullptr, CH, HID, HID, G4, 1);
    hipLaunchKernelGGL(cell2_k, dim3(cell_blocks), blk, 0, stream, gates, cbuf, hbuf, hb16, CH);

    // layer 1
    gemm(h_c,  wih1t, gates, lstmb + G4, CH, HID, G4, G4, 0);
    gemm(hb16, whh1t, gates, nullptr,    CH, HID, G4, G4, 1);
    gemm(cb16, wch1g, gates + 2 * HID, nullptr, CH, HID, HID, G4, 1);
    gemm(cb16, wch1f, gates + HID,     nullptr, CH, HID, HID, G4, 1);
    hipLaunchKernelGGL(cell1_k, dim3(cell_blocks), blk, 0, stream, gates, cbuf, cbuf, cb16, CH, 1);
    gemm(cb16, wch1o, gates + 3 * HID, nullptr, CH, HID, HID, G4, 1);
    hipLaunchKernelGGL(cell2_k, dim3(cell_blocks), blk, 0, stream, gates, cbuf, hbuf, hb16, CH);

    // output projection
    hipLaunchKernelGGL(out_k, dim3((CH * 64 + 255) / 256), blk, 0, stream,
                       hbuf, outW, outb, out + (size_t)r0 * 12, CH);
  }
}

// Round 5
// 1160.253 us; speedup vs baseline: 8.9290x; 1.3393x over previous
//
#include <hip/hip_runtime.h>
#include <cstddef>

#define N_NODES 20000
#define N_EDGES 320000
#define IN_CH   64
#define HID     512
#define G4      2048
#define BN_EPS  1e-5f

typedef __attribute__((ext_vector_type(8))) short short8;
typedef __attribute__((ext_vector_type(4))) float f32x4;

__device__ __forceinline__ float sigmoidf_(float x) {
  return 1.0f / (1.0f + expf(-x));
}

// fp32 -> bf16 (RNE)
__device__ __forceinline__ unsigned short f2b(float f) {
  unsigned int u = __float_as_uint(f);
  u += 0x7FFFu + ((u >> 16) & 1u);
  return (unsigned short)(u >> 16);
}
__device__ __forceinline__ float b2f(unsigned short u) {
  return __uint_as_float(((unsigned int)u) << 16);
}

__device__ __forceinline__ f32x4 mfma_bf16(short8 a, short8 b, f32x4 c) {
  asm volatile("v_mfma_f32_16x16x32_bf16 %0, %1, %2, %0"
               : "+v"(c) : "v"(a), "v"(b));
  return c;
}

__device__ __forceinline__ void gld_lds16(const unsigned short* g, unsigned short* l) {
  __builtin_amdgcn_global_load_lds(
      (const __attribute__((address_space(1))) unsigned int*)(const void*)g,
      (__attribute__((address_space(3))) unsigned int*)(void*)l, 16, 0, 0);
}

// ---------------- zero fill ----------------
__global__ __launch_bounds__(256) void zero_k(float* __restrict__ p, size_t n) {
  size_t i = ((size_t)blockIdx.x * 256 + threadIdx.x) * 4;
  if (i + 3 < n) {
    *(float4*)&p[i] = make_float4(0.f, 0.f, 0.f, 0.f);
  } else {
    for (; i < n; i++) p[i] = 0.f;
  }
}

// ---------------- f32 -> bf16 ----------------
__global__ __launch_bounds__(256) void cvt_k(const float* __restrict__ in,
                                             unsigned short* __restrict__ out, size_t n) {
  size_t i = ((size_t)blockIdx.x * 256 + threadIdx.x) * 4;
  if (i + 3 < n) {
    const float4 v = *(const float4*)&in[i];
    ushort4 o; o.x = f2b(v.x); o.y = f2b(v.y); o.z = f2b(v.z); o.w = f2b(v.w);
    *(ushort4*)&out[i] = o;
  } else {
    for (; i < n; i++) out[i] = f2b(in[i]);
  }
}

// ---------------- copy bf16 rows into stride-ldo buffer (concat build) ----------------
__global__ __launch_bounds__(256) void cpy16_k(const unsigned short* __restrict__ in,
                                               unsigned short* __restrict__ out,
                                               int rows, int ldo) {
  size_t gid = (size_t)blockIdx.x * 256 + threadIdx.x;
  size_t idx = gid * 4;
  if (idx >= (size_t)rows * HID) return;
  int row = (int)(idx >> 9);
  int col = (int)(idx & (HID - 1));
  *(ushort4*)&out[(size_t)row * ldo + col] = *(const ushort4*)&in[idx];
}

// ---------------- transpose + cvt: Wt[n*ldo + k] = bf16(W[k*ldw + n]) ----------------
__global__ void tcvt_k(const float* __restrict__ W, unsigned short* __restrict__ Wt,
                       int K, int NC, int ldw, int ldo) {
  __shared__ float tile[32][33];
  const int n0 = blockIdx.x * 32, k0 = blockIdx.y * 32;
  const int tx = threadIdx.x, ty = threadIdx.y;  // 32 x 8
  #pragma unroll
  for (int i = 0; i < 32; i += 8) {
    int k = k0 + ty + i, n = n0 + tx;
    tile[ty + i][tx] = (k < K && n < NC) ? W[(size_t)k * ldw + n] : 0.f;
  }
  __syncthreads();
  #pragma unroll
  for (int i = 0; i < 32; i += 8) {
    int n = n0 + ty + i, k = k0 + tx;
    if (n < NC && k < K) Wt[(size_t)n * ldo + k] = f2b(tile[tx][ty + i]);
  }
}

// ---------------- CSR build ----------------
__global__ __launch_bounds__(256) void hist_k(const int* __restrict__ dst,
                                              int* __restrict__ counts) {
  int e = blockIdx.x * 256 + threadIdx.x;
  if (e < N_EDGES) atomicAdd(&counts[dst[e]], 1);
}

__global__ __launch_bounds__(1024) void scan_k(const int* __restrict__ counts,
                                               int* __restrict__ offsets,
                                               int* __restrict__ pos, int n) {
  __shared__ int tmp[1024];
  __shared__ int carry_s;
  const int tid = threadIdx.x;
  if (tid == 0) carry_s = 0;
  __syncthreads();
  for (int base = 0; base < n; base += 1024) {
    int i = base + tid;
    int v = (i < n) ? counts[i] : 0;
    tmp[tid] = v;
    __syncthreads();
    #pragma unroll
    for (int off = 1; off < 1024; off <<= 1) {
      int t = (tid >= off) ? tmp[tid - off] : 0;
      __syncthreads();
      tmp[tid] += t;
      __syncthreads();
    }
    if (i < n) {
      int excl = carry_s + tmp[tid] - v;
      offsets[i] = excl;
      pos[i] = excl;
    }
    __syncthreads();
    if (tid == 1023) carry_s += tmp[1023];
    __syncthreads();
  }
  if (tid == 0) offsets[n] = carry_s;
}

__global__ __launch_bounds__(256) void fill_k(
    const int* __restrict__ src, const int* __restrict__ dst,
    const float* __restrict__ ew, int* __restrict__ pos,
    int* __restrict__ s_s, float* __restrict__ w_s) {
  int e = blockIdx.x * 256 + threadIdx.x;
  if (e >= N_EDGES) return;
  int p = atomicAdd(&pos[dst[e]], 1);
  s_s[p] = src[e];
  w_s[p] = ew[e];
}

// ---------------- aggregation gather (bf16 XW, fp32 accumulate) ----------------
__global__ __launch_bounds__(128) void gather_k(
    const unsigned short* __restrict__ XW, const int* __restrict__ offsets,
    const int* __restrict__ s_s, const float* __restrict__ w_s,
    float* __restrict__ H) {
  const int n = blockIdx.x;
  const int t = threadIdx.x;
  const int beg = offsets[n], end = offsets[n + 1];
  float4 acc = make_float4(0.f, 0.f, 0.f, 0.f);
  for (int i = beg; i < end; i++) {
    const int   s = s_s[i];
    const float w = w_s[i];
    const ushort4 v = *(const ushort4*)&XW[(size_t)s * HID + t * 4];
    acc.x = fmaf(w, b2f(v.x), acc.x);
    acc.y = fmaf(w, b2f(v.y), acc.y);
    acc.z = fmaf(w, b2f(v.z), acc.z);
    acc.w = fmaf(w, b2f(v.w), acc.w);
  }
  *(float4*)&H[(size_t)n * HID + t * 4] = acc;
}

// ---------------- bf16 MFMA GEMM ----------------
// C(f32) or C16(bf16) [M,NC] (+)= A[M,K](bf16) * Bt[NC,K](bf16)^T (+bias)
// 128x128 tile, BK=32, 256 thr. NC%128==0, K%32==0. C16 mode: acc=0, no bias.
__global__ __launch_bounds__(256) void gemm_bf16_k(
    const unsigned short* __restrict__ A, const unsigned short* __restrict__ Bt,
    float* __restrict__ C, unsigned short* __restrict__ C16,
    const float* __restrict__ bias,
    int M, int K, int NC, int ldc, int acc)
{
  __shared__ unsigned short As[128 * 32];
  __shared__ unsigned short Bs[128 * 32];
  const int row0 = blockIdx.x * 128;
  const int col0 = blockIdx.y * 128;
  const int t    = threadIdx.x;
  const int lane = t & 63;
  const int w    = t >> 6;
  const int wr   = w >> 1, wc = w & 1;
  const int q    = lane >> 4;
  const int l16  = lane & 15;

  f32x4 accr[4][4] = {};

  for (int k0 = 0; k0 < K; k0 += 32) {
    #pragma unroll
    for (int i = 0; i < 2; i++) {
      int c  = w * 64 + lane + i * 256;
      int r  = c >> 2, kq = c & 3;
      int gr = row0 + r; if (gr > M - 1) gr = M - 1;
      gld_lds16(A + (size_t)gr * K + k0 + kq * 8, As + (size_t)(w * 64 + i * 256) * 8);
    }
    #pragma unroll
    for (int i = 0; i < 2; i++) {
      int c = w * 64 + lane + i * 256;
      int r = c >> 2, kq = c & 3;
      gld_lds16(Bt + (size_t)(col0 + r) * K + k0 + kq * 8, Bs + (size_t)(w * 64 + i * 256) * 8);
    }
    __syncthreads();

    short8 af[4], bf[4];
    #pragma unroll
    for (int mi = 0; mi < 4; mi++)
      af[mi] = *(const short8*)&As[(wr * 64 + mi * 16 + l16) * 32 + q * 8];
    #pragma unroll
    for (int ni = 0; ni < 4; ni++)
      bf[ni] = *(const short8*)&Bs[(wc * 64 + ni * 16 + l16) * 32 + q * 8];
    #pragma unroll
    for (int mi = 0; mi < 4; mi++)
      #pragma unroll
      for (int ni = 0; ni < 4; ni++)
        accr[mi][ni] = mfma_bf16(af[mi], bf[ni], accr[mi][ni]);
    __syncthreads();
  }

  #pragma unroll
  for (int mi = 0; mi < 4; mi++) {
    #pragma unroll
    for (int ni = 0; ni < 4; ni++) {
      int col = col0 + wc * 64 + ni * 16 + l16;
      #pragma unroll
      for (int r = 0; r < 4; r++) {
        int row = row0 + wr * 64 + mi * 16 + q * 4 + r;
        if (row < M) {
          float v = accr[mi][ni][r];
          if (C16) {
            C16[(size_t)row * ldc + col] = f2b(v);
          } else {
            float* cp = &C[(size_t)row * ldc + col];
            if (acc)       *cp += v;
            else if (bias) *cp  = v + bias[col];
            else           *cp  = v;
          }
        }
      }
    }
  }
}

// ---------------- BN stats ----------------
__global__ __launch_bounds__(256) void bn_stats_k(
    const float* __restrict__ H, float* __restrict__ stats, int N)
{
  const int tx = threadIdx.x & 63;
  const int ty = threadIdx.x >> 6;
  const int col = blockIdx.x * 64 + tx;
  float s1 = 0.f, s2 = 0.f;
  for (int r = blockIdx.y * 4 + ty; r < N; r += gridDim.y * 4) {
    float v = H[(size_t)r * HID + col];
    s1 += v; s2 += v * v;
  }
  __shared__ float red[2][4][64];
  red[0][ty][tx] = s1;
  red[1][ty][tx] = s2;
  __syncthreads();
  if (ty == 0) {
    s1 = red[0][0][tx] + red[0][1][tx] + red[0][2][tx] + red[0][3][tx];
    s2 = red[1][0][tx] + red[1][1][tx] + red[1][2][tx] + red[1][3][tx];
    atomicAdd(&stats[col], s1);
    atomicAdd(&stats[HID + col], s2);
  }
}

// ---------------- BN apply + ReLU -> bf16 ----------------
__global__ __launch_bounds__(256) void bn_apply_k(
    const float* __restrict__ H, const float* __restrict__ stats,
    const float* __restrict__ gamma, const float* __restrict__ beta,
    unsigned short* __restrict__ out, int N)
{
  size_t gid = (size_t)blockIdx.x * 256 + threadIdx.x;
  size_t idx = gid * 4;
  if (idx >= (size_t)N * HID) return;
  int col = (int)(idx & (HID - 1));
  const float4 v = *(const float4*)&H[idx];
  float r[4] = {v.x, v.y, v.z, v.w};
  ushort4 o;
  unsigned short* op = &o.x;
  #pragma unroll
  for (int i = 0; i < 4; i++) {
    int c = col + i;
    float mean = stats[c] * (1.0f / N);
    float var  = stats[HID + c] * (1.0f / N) - mean * mean;
    float scale = gamma[c] / sqrtf(var + BN_EPS);
    float shift = beta[c] - mean * scale;
    op[i] = f2b(fmaxf(fmaf(r[i], scale, shift), 0.0f));
  }
  *(ushort4*)&out[idx] = o;
}

// ---------------- LSTM cell part 1: cy; dual-write fp32 + bf16 ----------------
__global__ __launch_bounds__(256) void cell1_k(
    const float* __restrict__ gates, const float* __restrict__ cin,
    float* __restrict__ cout, unsigned short* __restrict__ cout16,
    int rows, int hasC)
{
  size_t gid = (size_t)blockIdx.x * 256 + threadIdx.x;
  if (gid >= (size_t)rows * HID) return;
  size_t row = gid >> 9;
  int    col = (int)(gid & (HID - 1));
  const float* g = &gates[row * G4];
  float ig = sigmoidf_(g[col]);
  float gg = tanhf(g[2 * HID + col]);
  float c;
  if (hasC) {
    float fg = sigmoidf_(g[HID + col]);
    c = fg * cin[gid] + ig * gg;
  } else {
    c = ig * gg;
  }
  cout[gid] = c;
  cout16[gid] = f2b(c);
}

// ---------------- LSTM cell part 2: hy; optional bf16 write at stride ----------------
__global__ __launch_bounds__(256) void cell2_k(
    const float* __restrict__ gates, const float* __restrict__ cy,
    float* __restrict__ hy, unsigned short* __restrict__ hy16, int ld16, int rows)
{
  size_t gid = (size_t)blockIdx.x * 256 + threadIdx.x;
  if (gid >= (size_t)rows * HID) return;
  size_t row = gid >> 9;
  int    col = (int)(gid & (HID - 1));
  float og = sigmoidf_(gates[row * G4 + 3 * HID + col]);
  float h = og * tanhf(cy[gid]);
  hy[gid] = h;
  if (hy16) hy16[row * ld16 + col] = f2b(h);
}

// ---------------- output projection (fp32) ----------------
__global__ __launch_bounds__(256) void out_k(
    const float* __restrict__ Hh, const float* __restrict__ W,
    const float* __restrict__ b, float* __restrict__ out, int rows)
{
  int wave = (int)(((size_t)blockIdx.x * 256 + threadIdx.x) >> 6);
  int lane = threadIdx.x & 63;
  if (wave >= rows) return;
  const float* hr = &Hh[(size_t)wave * HID];
  float acc[12] = {};
  for (int k = lane; k < HID; k += 64) {
    float hv = hr[k];
    const float* wr = &W[k * 12];
    #pragma unroll
    for (int p = 0; p < 12; p++) acc[p] = fmaf(hv, wr[p], acc[p]);
  }
  #pragma unroll
  for (int p = 0; p < 12; p++) {
    float v = acc[p];
    #pragma unroll
    for (int off = 32; off > 0; off >>= 1) v += __shfl_down(v, off);
    if (lane == 0) out[(size_t)wave * 12 + p] = v + b[p];
  }
}

extern "C" void kernel_launch(void* const* d_in, const int* in_sizes, int n_in,
                              void* d_out, int out_size, void* d_ws, size_t ws_size,
                              hipStream_t stream) {
  const float* x     = (const float*)d_in[0];
  const int*   ei    = (const int*)d_in[1];
  const float* ew    = (const float*)d_in[2];
  const float* gcn0W = (const float*)d_in[3];
  const float* gcnW  = (const float*)d_in[5];
  const float* gamma = (const float*)d_in[7];
  const float* beta  = (const float*)d_in[8];
  const float* wih   = (const float*)d_in[9];
  const float* whh   = (const float*)d_in[10];
  const float* wch   = (const float*)d_in[11];
  const float* lstmb = (const float*)d_in[12];
  const float* outW  = (const float*)d_in[13];
  const float* outb  = (const float*)d_in[14];
  float* out = (float*)d_out;

  const int* src = ei;
  const int* dst = ei + N_EDGES;

  // chunk size: 10000 if workspace permits (~210 MB), else 5000 (~138 MB).
  // ws_size is constant across calls -> branch is graph-capture-safe.
  const int CH = (ws_size >= (size_t)215000000) ? 10000 : 5000;
  const int NCHUNK = N_NODES / CH;

  // -------- workspace layout --------
  const size_t NH = (size_t)N_NODES * HID;
  float* ws = (float*)d_ws;
  float* gates = ws;                                 // CH*2048 fp32
  float* bufH  = gates + (size_t)CH * G4;            // NH fp32 (gather H | cbuf+hbuf)
  unsigned short* hbA16 = (unsigned short*)(bufH + NH);  // NH bf16
  unsigned short* hbB16 = hbA16 + NH;                    // NH bf16
  unsigned short* x16   = hbB16 + NH;                    // N*64
  unsigned short* g0t   = x16 + (size_t)N_NODES * IN_CH;
  unsigned short* g1t   = g0t   + 512 * 64;
  unsigned short* g2t   = g1t   + 512 * 512;
  unsigned short* wih0t = g2t   + 512 * 512;             // [2048,512]
  unsigned short* wcat  = wih0t + (size_t)2048 * 512;    // [2048,1024] = [Wih1^T | Whh1^T]
  unsigned short* wch0ot= wcat  + (size_t)2048 * 1024;   // [512,512]
  unsigned short* wgf   = wch0ot + 512 * 512;            // [1024,512] = [f^T ; g^T]
  unsigned short* wch1o = wgf   + (size_t)1024 * 512;    // [512,512]
  unsigned short* wend  = wch1o + 512 * 512;
  // a16 (concat activations) + cb16: overlay into hbB16 when CH==5000, else separate
  unsigned short *a16, *cb16, *tail16;
  if (CH == 5000) {
    a16  = hbB16;                       // CH*1024 = 5.12M <= NH
    cb16 = hbB16 + (size_t)CH * 1024;   // CH*512; total 7.68M <= NH ok
    tail16 = wend;
  } else {
    a16  = wend;
    cb16 = a16 + (size_t)CH * 1024;
    tail16 = cb16 + (size_t)CH * HID;
  }
  float* stats = (float*)tail16;                     // 1024 fp32
  int*   csr   = (int*)(stats + 1024);
  int*   counts  = csr;
  int*   offsets = csr + 20032;
  int*   cpos    = csr + 40064;
  int*   s_s     = csr + 60096;
  float* w_s     = (float*)(csr + 380096);

  float* cbuf = bufH;                        // CH*512 fp32
  float* hbuf = bufH + (size_t)CH * HID;     // CH*512 fp32

  const dim3 blk(256);
  auto gemm = [&](const unsigned short* A, const unsigned short* Bt, float* C,
                  unsigned short* C16, const float* bias,
                  int M, int K, int NC, int ldc, int acc) {
    dim3 grid((M + 127) / 128, NC / 128);
    hipLaunchKernelGGL(gemm_bf16_k, grid, blk, 0, stream, A, Bt, C, C16, bias,
                       M, K, NC, ldc, acc);
  };
  auto tcvt = [&](const float* W, unsigned short* Wt, int K, int NC, int ldw, int ldo) {
    dim3 grid((NC + 31) / 32, (K + 31) / 32);
    hipLaunchKernelGGL(tcvt_k, grid, dim3(32, 8), 0, stream, W, Wt, K, NC, ldw, ldo);
  };
  auto zero = [&](float* p, size_t n) {
    hipLaunchKernelGGL(zero_k, dim3((unsigned)((n / 4 + 255) / 256)), blk, 0, stream, p, n);
  };

  // -------- weight prep --------
  const float* wih1 = wih + (size_t)HID * G4;
  const float* whh1 = whh + (size_t)HID * G4;
  const float* wch1 = wch + (size_t)HID * 3 * HID;
  tcvt(gcn0W, g0t, IN_CH, HID, HID, IN_CH);
  tcvt(gcnW,                     g1t, HID, HID, HID, HID);
  tcvt(gcnW + (size_t)HID * HID, g2t, HID, HID, HID, HID);
  tcvt(wih,  wih0t, HID, G4, G4, HID);
  tcvt(wih1, wcat,       HID, G4, G4, 1024);   // K-slice [0:512]
  tcvt(whh1, wcat + 512, HID, G4, G4, 1024);   // K-slice [512:1024]
  tcvt(wch + 2 * HID, wch0ot, HID, HID, 3 * HID, HID);     // Wch0[:,2H:3H]
  tcvt(wch1 + HID, wgf,             HID, HID, 3 * HID, HID); // f -> out cols [H:2H]
  tcvt(wch1,       wgf + 512 * 512, HID, HID, 3 * HID, HID); // g -> out cols [2H:3H]
  tcvt(wch1 + 2 * HID, wch1o, HID, HID, 3 * HID, HID);
  hipLaunchKernelGGL(cvt_k, dim3((N_NODES * IN_CH / 4 + 255) / 256), blk, 0, stream,
                     x, x16, (size_t)N_NODES * IN_CH);

  // -------- CSR build --------
  const int e_blocks = (N_EDGES + 255) / 256;
  zero((float*)counts, N_NODES);
  hipLaunchKernelGGL(hist_k, dim3(e_blocks), blk, 0, stream, dst, counts);
  hipLaunchKernelGGL(scan_k, dim3(1), dim3(1024), 0, stream, counts, offsets, cpos, N_NODES);
  hipLaunchKernelGGL(fill_k, dim3(e_blocks), blk, 0, stream, src, dst, ew, cpos, s_s, w_s);

  // -------- GCN stack (XW in bf16, staged into the layer's dead h16 buffer) -----
  const unsigned short* gWt[3] = {g0t, g1t, g2t};
  const int             gK[3]  = {IN_CH, HID, HID};
  const unsigned short* gA[3]  = {x16, hbA16, hbB16};
  unsigned short*       gO[3]  = {hbA16, hbB16, hbA16};
  unsigned short*       gXW[3] = {hbB16, hbB16, hbA16};  // dead buffer per layer
  for (int l = 0; l < 3; l++) {
    gemm(gA[l], gWt[l], nullptr, gXW[l], nullptr, N_NODES, gK[l], HID, HID, 0);
    hipLaunchKernelGGL(gather_k, dim3(N_NODES), dim3(128), 0, stream,
                       gXW[l], offsets, s_s, w_s, bufH);
    zero(stats, 2 * HID);
    hipLaunchKernelGGL(bn_stats_k, dim3(8, 64), blk, 0, stream, bufH, stats, N_NODES);
    hipLaunchKernelGGL(bn_apply_k, dim3((unsigned)(NH / 4 / 256)), blk, 0, stream,
                       bufH, stats, gamma + l * HID, beta + l * HID, gO[l], N_NODES);
  }
  unsigned short* hfin16 = hbA16;

  // -------- LSTM + output, chunked --------
  for (int ci = 0; ci < NCHUNK; ci++) {
    const int r0 = ci * CH;
    const unsigned short* h_c = hfin16 + (size_t)r0 * HID;
    const int cell_blocks = (int)(((size_t)CH * HID + 255) / 256);
    const int cpy_blocks  = (int)(((size_t)CH * HID / 4 + 255) / 256);

    // build concat left half: a16[r,0:512] = h
    hipLaunchKernelGGL(cpy16_k, dim3(cpy_blocks), blk, 0, stream, h_c, a16, CH, 1024);

    // layer 0 (h=c=0): gates = h@Wih0 + b0
    gemm(h_c, wih0t, gates, nullptr, lstmb, CH, HID, G4, G4, 0);
    hipLaunchKernelGGL(cell1_k, dim3(cell_blocks), blk, 0, stream,
                       gates, (const float*)nullptr, cbuf, cb16, CH, 0);
    gemm(cb16, wch0ot, gates + 3 * HID, nullptr, nullptr, CH, HID, HID, G4, 1);
    // hy0 -> fp32 hbuf + bf16 into concat right half
    hipLaunchKernelGGL(cell2_k, dim3(cell_blocks), blk, 0, stream,
                       gates, cbuf, hbuf, a16 + HID, 1024, CH);

    // layer 1: gates = [h|hy0] @ [Wih1;Whh1] + b1   (single K=1024 GEMM)
    gemm(a16, wcat, gates, nullptr, lstmb + G4, CH, 1024, G4, G4, 0);
    // fused f+g peepholes: gates[:,H:3H] += c0 @ [Wch1_f | Wch1_g]
    gemm(cb16, wgf, gates + HID, nullptr, nullptr, CH, HID, 1024, G4, 1);
    hipLaunchKernelGGL(cell1_k, dim3(cell_blocks), blk, 0, stream,
                       gates, cbuf, cbuf, cb16, CH, 1);
    gemm(cb16, wch1o, gates + 3 * HID, nullptr, nullptr, CH, HID, HID, G4, 1);
    hipLaunchKernelGGL(cell2_k, dim3(cell_blocks), blk, 0, stream,
                       gates, cbuf, hbuf, (unsigned short*)nullptr, 0, CH);

    // output projection
    hipLaunchKernelGGL(out_k, dim3((CH * 64 + 255) / 256), blk, 0, stream,
                       hbuf, outW, outb, out + (size_t)r0 * 12, CH);
  }
}